// Round 1
// baseline (3119.552 us; speedup 1.0000x reference)
//
#include <hip/hip_runtime.h>
#include <hip/hip_bf16.h>

typedef float f4 __attribute__((ext_vector_type(4)));

// ---------------------------------------------------------------------------
// Stem: 512x512x3 --7x7 s2 pad2--> 256x256x64, ReLU.
// Block = 16x16 output tile, all 64 couts. Input patch (37x37x3) + weights in LDS.
// ---------------------------------------------------------------------------
__global__ __launch_bounds__(256) void stem_kernel(
    const float* __restrict__ in, const float* __restrict__ w,
    float* __restrict__ out)
{
  __shared__ float in_lds[37 * 37 * 3];   // 4107 floats
  __shared__ float w_lds[7 * 7 * 3 * 64]; // 9408 floats
  const int tid = threadIdx.x;
  const int ty0 = (blockIdx.x >> 4) * 16;
  const int tx0 = (blockIdx.x & 15) * 16;

  for (int idx = tid; idx < 9408; idx += 256) w_lds[idx] = w[idx];
  for (int idx = tid; idx < 4107; idx += 256) {
    int ci = idx % 3;
    int rem = idx / 3;
    int ix = rem % 37, iy = rem / 37;
    int gy = ty0 * 2 - 2 + iy, gx = tx0 * 2 - 2 + ix;
    float v = 0.f;
    if ((unsigned)gy < 512u && (unsigned)gx < 512u)
      v = in[(gy * 512 + gx) * 3 + ci];
    in_lds[idx] = v;
  }
  __syncthreads();

  const int co = (tid & 15) * 4;
  const int py = tid >> 4;  // each thread: one output row (16 px) x 4 couts
  f4 acc[16];
#pragma unroll
  for (int px = 0; px < 16; ++px) acc[px] = (f4)0.f;

  for (int ky = 0; ky < 7; ++ky)
    for (int kx = 0; kx < 7; ++kx)
#pragma unroll
      for (int ci = 0; ci < 3; ++ci) {
        f4 wv = *(const f4*)&w_lds[(((ky * 7 + kx) * 3) + ci) * 64 + co];
        const float* ip = &in_lds[((2 * py + ky) * 37 + kx) * 3 + ci];
#pragma unroll
        for (int px = 0; px < 16; ++px) {
          float iv = ip[px * 6];
          acc[px] += iv * wv;
        }
      }

#pragma unroll
  for (int px = 0; px < 16; ++px) {
    int oy = ty0 + py, ox = tx0 + px;
    f4 o = acc[px];
#pragma unroll
    for (int c = 0; c < 4; ++c) o[c] = fmaxf(o[c], 0.f);
    *(f4*)&out[(oy * 256 + ox) * 64 + co] = o;
  }
}

// ---------------------------------------------------------------------------
// Generic implicit-GEMM conv, NHWC, fp32. Tile: 64 pixels x 64 couts,
// 256 threads, 4x4 outputs/thread, K staged in chunks of 32 channels.
// Requires: C_in % 32 == 0, C_out % 64 == 0, NPIX % 64 == 0, W_out = 1<<wshift.
// ---------------------------------------------------------------------------
__global__ __launch_bounds__(256) void conv_ig_kernel(
    const float* __restrict__ in, const float* __restrict__ w,
    float* __restrict__ out,
    int H_in, int W_in, int C_in, int wshift, int C_out,
    int KH, int KW, int stride, int pad, int relu)
{
  __shared__ __align__(16) float As[64][36];  // [pix][ci], +4 pad: b128-friendly, conflict-free
  __shared__ __align__(16) float Bs[32][64];  // [ci][co]
  const int tid = threadIdx.x;
  const int pix_base = blockIdx.x * 64;
  const int co_base = blockIdx.y * 64;
  const int wmask = (1 << wshift) - 1;

  const int tx = tid & 15, ty = tid >> 4;
  const int p0 = ty * 4;
  const int co_lo = tx * 4;

  const int s_ci = tid & 31;
  const int s_pix0 = tid >> 5;  // + r*8
  const int b_co = tid & 63;
  const int b_ci0 = tid >> 6;   // + r*4

  f4 acc[4];
#pragma unroll
  for (int i = 0; i < 4; ++i) acc[i] = (f4)0.f;

  for (int ky = 0; ky < KH; ++ky) {
    for (int kx = 0; kx < KW; ++kx) {
      for (int ci0 = 0; ci0 < C_in; ci0 += 32) {
        // stage A: 64 pixels x 32 channels (coalesced 32-ci runs)
#pragma unroll
        for (int r = 0; r < 8; ++r) {
          int pix = s_pix0 + r * 8;
          int p = pix_base + pix;
          int oy = p >> wshift, ox = p & wmask;
          int iy = oy * stride - pad + ky;
          int ix = ox * stride - pad + kx;
          float v = 0.f;
          if ((unsigned)iy < (unsigned)H_in && (unsigned)ix < (unsigned)W_in)
            v = in[(iy * W_in + ix) * C_in + ci0 + s_ci];
          As[pix][s_ci] = v;
        }
        // stage B: 32 channels x 64 couts (coalesced co runs)
        {
          const float* wp = &w[((ky * KW + kx) * C_in + ci0) * C_out + co_base + b_co];
#pragma unroll
          for (int r = 0; r < 8; ++r) {
            int bci = b_ci0 + r * 4;
            Bs[bci][b_co] = wp[bci * C_out];
          }
        }
        __syncthreads();
#pragma unroll
        for (int kk = 0; kk < 32; kk += 4) {
          f4 a[4], b[4];
#pragma unroll
          for (int i = 0; i < 4; ++i) a[i] = *(const f4*)&As[p0 + i][kk];
#pragma unroll
          for (int j = 0; j < 4; ++j) b[j] = *(const f4*)&Bs[kk + j][co_lo];
#pragma unroll
          for (int j = 0; j < 4; ++j)
#pragma unroll
            for (int i = 0; i < 4; ++i)
              acc[i] += a[i][j] * b[j];
        }
        __syncthreads();
      }
    }
  }

#pragma unroll
  for (int i = 0; i < 4; ++i) {
    int p = pix_base + p0 + i;
    f4 o = acc[i];
    if (relu) {
#pragma unroll
      for (int c = 0; c < 4; ++c) o[c] = fmaxf(o[c], 0.f);
    }
    *(f4*)&out[p * C_out + co_base + co_lo] = o;
  }
}

// ---------------------------------------------------------------------------
// 1x1 conv (= GEMM over pixels) with optional fused nearest-neighbor up2 add.
// Block: 64 couts x 16 pixels; thread = 1 cout x 4 pixels.
// ---------------------------------------------------------------------------
__global__ __launch_bounds__(256) void conv1x1_kernel(
    const float* __restrict__ in,   // [NPIX][C_in]
    const float* __restrict__ w,    // [C_in][C_out]
    const float* __restrict__ res,  // [NPIX/4][C_out] (half-res) or nullptr
    float* __restrict__ out,        // [NPIX][C_out]
    int C_in, int C_out, int wshift, int add_up2)
{
  const int tid = threadIdx.x;
  const int co = blockIdx.y * 64 + (tid & 63);
  const int pg = tid >> 6;
  const int p_base = blockIdx.x * 16 + pg * 4;
  const int wmask = (1 << wshift) - 1;

  float acc[4] = {0.f, 0.f, 0.f, 0.f};
  for (int ci = 0; ci < C_in; ci += 4) {
    float w0 = w[(ci + 0) * C_out + co];
    float w1 = w[(ci + 1) * C_out + co];
    float w2 = w[(ci + 2) * C_out + co];
    float w3 = w[(ci + 3) * C_out + co];
#pragma unroll
    for (int q = 0; q < 4; ++q) {
      f4 iv = *(const f4*)&in[(p_base + q) * C_in + ci];
      acc[q] += iv[0] * w0 + iv[1] * w1 + iv[2] * w2 + iv[3] * w3;
    }
  }
#pragma unroll
  for (int q = 0; q < 4; ++q) {
    int p = p_base + q;
    float v = acc[q];
    if (add_up2) {
      int oy = p >> wshift, ox = p & wmask;
      v += res[(((oy >> 1) << (wshift - 1)) + (ox >> 1)) * C_out + co];
    }
    out[p * C_out + co] = v;
  }
}

// ---------------------------------------------------------------------------
// obj head (1x1, 256->1) + sigmoid. One thread per output pixel.
// ---------------------------------------------------------------------------
__global__ __launch_bounds__(256) void obj_sigmoid_kernel(
    const float* __restrict__ t, const float* __restrict__ wobj,
    float* __restrict__ scores)
{
  __shared__ float wl[256];
  const int tid = threadIdx.x;
  wl[tid] = wobj[tid];
  __syncthreads();
  const int p = blockIdx.x * 256 + tid;
  float acc = 0.f;
  for (int ci = 0; ci < 256; ci += 4) {
    f4 tv = *(const f4*)&t[p * 256 + ci];
    acc += tv[0] * wl[ci] + tv[1] * wl[ci + 1] + tv[2] * wl[ci + 2] + tv[3] * wl[ci + 3];
  }
  scores[p] = 1.f / (1.f + expf(-acc));
}

// ---------------------------------------------------------------------------
// Greedy NMS, 100 iterations, faithful to reference (first-index argmax ties,
// NEG = -1e30, valid = s > -5e29, iou > 0.5, +1e-9 denom).
// Boxes live on a 64x64 grid: k -> i=k>>6 (x), j=k&63 (y); side 0.1, clip [0,1].
// IoU is 0 unless |di|<=6 && |dj|<=6 (7/63 > 0.1), so suppression is filtered.
// ---------------------------------------------------------------------------
__global__ __launch_bounds__(256) void nms_kernel(
    const float* __restrict__ scores, float* __restrict__ out)
{
  __shared__ float sw[4096];
  __shared__ float rv[4];
  __shared__ int ri[4];
  __shared__ float sel[4];
  __shared__ int selij[2];
  const int tid = threadIdx.x;
  const float inv63 = 1.0f / 63.0f;

#pragma unroll
  for (int r = 0; r < 16; ++r) sw[r * 256 + tid] = scores[r * 256 + tid];
  __syncthreads();

  for (int it = 0; it < 100; ++it) {
    // local argmax over 16 strided entries (k increasing -> first-max kept)
    float bv = -3.0e38f;
    int bi = 0;
#pragma unroll
    for (int r = 0; r < 16; ++r) {
      int k = r * 256 + tid;
      float v = sw[k];
      if (v > bv) { bv = v; bi = k; }
    }
    // wave reduce (64 lanes), min-index tiebreak
#pragma unroll
    for (int off = 32; off > 0; off >>= 1) {
      float ov = __shfl_down(bv, off);
      int oi = __shfl_down(bi, off);
      if (ov > bv || (ov == bv && oi < bi)) { bv = ov; bi = oi; }
    }
    if ((tid & 63) == 0) { rv[tid >> 6] = bv; ri[tid >> 6] = bi; }
    __syncthreads();
    if (tid == 0) {
      float v = rv[0];
      int s = ri[0];
#pragma unroll
      for (int wv = 1; wv < 4; ++wv)
        if (rv[wv] > v || (rv[wv] == v && ri[wv] < s)) { v = rv[wv]; s = ri[wv]; }
      int si = s >> 6, sj = s & 63;
      float y = sj * inv63, x = si * inv63;
      float b0 = fmaxf(y - 0.05f, 0.f);
      float b1 = fmaxf(x - 0.05f, 0.f);
      float b2 = fminf(y + 0.05f, 1.f);
      float b3 = fminf(x + 0.05f, 1.f);
      bool valid = v > -5.0e29f;
      out[it * 4 + 0] = valid ? b0 : 0.f;
      out[it * 4 + 1] = valid ? b1 : 0.f;
      out[it * 4 + 2] = valid ? b2 : 0.f;
      out[it * 4 + 3] = valid ? b3 : 0.f;
      out[400 + it] = valid ? v : 0.f;
      sel[0] = b0; sel[1] = b1; sel[2] = b2; sel[3] = b3;
      selij[0] = si; selij[1] = sj;
    }
    __syncthreads();
    const float a0 = sel[0], a1 = sel[1], a2 = sel[2], a3 = sel[3];
    const int si = selij[0], sj = selij[1];
    const float barea = (a2 - a0) * (a3 - a1);
#pragma unroll
    for (int r = 0; r < 16; ++r) {
      int k = r * 256 + tid;
      int i = k >> 6, j = k & 63;
      int di = i - si; di = di < 0 ? -di : di;
      int dj = j - sj; dj = dj < 0 ? -dj : dj;
      if (di <= 6 && dj <= 6) {
        float y = j * inv63, x = i * inv63;
        float c0 = fmaxf(y - 0.05f, 0.f), c1 = fmaxf(x - 0.05f, 0.f);
        float c2 = fminf(y + 0.05f, 1.f), c3 = fminf(x + 0.05f, 1.f);
        float yy1 = fmaxf(a0, c0), xx1 = fmaxf(a1, c1);
        float yy2 = fminf(a2, c2), xx2 = fminf(a3, c3);
        float inter = fmaxf(yy2 - yy1, 0.f) * fmaxf(xx2 - xx1, 0.f);
        float carea = (c2 - c0) * (c3 - c1);
        float iou = inter / (barea + carea - inter + 1e-9f);
        if (iou > 0.5f) sw[k] = -1.0e30f;
      }
    }
    __syncthreads();
  }
}

// ---------------------------------------------------------------------------
extern "C" void kernel_launch(void* const* d_in, const int* in_sizes, int n_in,
                              void* d_out, int out_size, void* d_ws, size_t ws_size,
                              hipStream_t stream) {
  const float* x      = (const float*)d_in[0];
  const float* w_stem = (const float*)d_in[1];
  const float* w_c2   = (const float*)d_in[2];
  const float* w_c3   = (const float*)d_in[3];
  const float* w_c4   = (const float*)d_in[4];
  const float* w_c5   = (const float*)d_in[5];
  const float* l3     = (const float*)d_in[6];
  const float* l4     = (const float*)d_in[7];
  const float* l5     = (const float*)d_in[8];
  const float* o3     = (const float*)d_in[9];
  // d_in[10]=o4, d_in[11]=o5, d_in[14]=w_box: dead code in the reference.
  const float* w_rpn  = (const float*)d_in[12];
  const float* w_obj  = (const float*)d_in[13];
  float* out = (float*)d_out;
  float* ws = (float*)d_ws;

  float* S   = ws;              // 256*256*64   = 4194304
  float* C2  = S   + 4194304;   // 128*128*256  = 4194304
  float* C3  = C2  + 4194304;   // 64*64*512    = 2097152
  float* C4  = C3  + 2097152;   // 32*32*1024   = 1048576
  float* C5  = C4  + 1048576;   // 16*16*2048   = 524288
  float* P5  = C5  + 524288;    // 16*16*256    = 65536
  float* P4  = P5  + 65536;     // 32*32*256    = 262144
  float* P3P = P4  + 262144;    // 64*64*256    = 1048576
  float* P3  = P3P + 1048576;   // 1048576
  float* T   = P3  + 1048576;   // 1048576
  float* SC  = T   + 1048576;   // 4096
  // total ~59.3 MiB of workspace

  // backbone
  stem_kernel<<<256, 256, 0, stream>>>(x, w_stem, S);
  conv_ig_kernel<<<dim3(16384 / 64, 256 / 64), 256, 0, stream>>>(
      S, w_c2, C2, 256, 256, 64, 7, 256, 3, 3, 2, 0, 1);
  conv_ig_kernel<<<dim3(4096 / 64, 512 / 64), 256, 0, stream>>>(
      C2, w_c3, C3, 128, 128, 256, 6, 512, 3, 3, 2, 0, 1);
  conv_ig_kernel<<<dim3(1024 / 64, 1024 / 64), 256, 0, stream>>>(
      C3, w_c4, C4, 64, 64, 512, 5, 1024, 3, 3, 2, 0, 1);
  conv_ig_kernel<<<dim3(256 / 64, 2048 / 64), 256, 0, stream>>>(
      C4, w_c5, C5, 32, 32, 1024, 4, 2048, 3, 3, 2, 0, 1);
  // FPN laterals (+ fused up2 add)
  conv1x1_kernel<<<dim3(256 / 16, 4), 256, 0, stream>>>(C5, l5, nullptr, P5, 2048, 256, 4, 0);
  conv1x1_kernel<<<dim3(1024 / 16, 4), 256, 0, stream>>>(C4, l4, P5, P4, 1024, 256, 5, 1);
  conv1x1_kernel<<<dim3(4096 / 16, 4), 256, 0, stream>>>(C3, l3, P4, P3P, 512, 256, 6, 1);
  // p3 output conv (no relu)
  conv_ig_kernel<<<dim3(64, 4), 256, 0, stream>>>(
      P3P, o3, P3, 64, 64, 256, 6, 256, 3, 3, 1, 1, 0);
  // RPN shared conv (relu) + obj head + sigmoid
  conv_ig_kernel<<<dim3(64, 4), 256, 0, stream>>>(
      P3, w_rpn, T, 64, 64, 256, 6, 256, 3, 3, 1, 1, 1);
  obj_sigmoid_kernel<<<16, 256, 0, stream>>>(T, w_obj, SC);
  // NMS
  nms_kernel<<<1, 256, 0, stream>>>(SC, out);
}

// Round 2
// 1616.961 us; speedup vs baseline: 1.9293x; 1.9293x over previous
//
#include <hip/hip_runtime.h>
#include <hip/hip_bf16.h>

typedef float f4 __attribute__((ext_vector_type(4)));

// ---------------------------------------------------------------------------
// Stem: 512x512x3 --7x7 s2 pad2--> 256x256x64, ReLU.
// ---------------------------------------------------------------------------
__global__ __launch_bounds__(256) void stem_kernel(
    const float* __restrict__ in, const float* __restrict__ w,
    float* __restrict__ out)
{
  __shared__ float in_lds[37 * 37 * 3];   // 4107 floats
  __shared__ float w_lds[7 * 7 * 3 * 64]; // 9408 floats
  const int tid = threadIdx.x;
  const int ty0 = (blockIdx.x >> 4) * 16;
  const int tx0 = (blockIdx.x & 15) * 16;

  for (int idx = tid; idx < 9408; idx += 256) w_lds[idx] = w[idx];
  for (int idx = tid; idx < 4107; idx += 256) {
    int ci = idx % 3;
    int rem = idx / 3;
    int ix = rem % 37, iy = rem / 37;
    int gy = ty0 * 2 - 2 + iy, gx = tx0 * 2 - 2 + ix;
    float v = 0.f;
    if ((unsigned)gy < 512u && (unsigned)gx < 512u)
      v = in[(gy * 512 + gx) * 3 + ci];
    in_lds[idx] = v;
  }
  __syncthreads();

  const int co = (tid & 15) * 4;
  const int py = tid >> 4;
  f4 acc[16];
#pragma unroll
  for (int px = 0; px < 16; ++px) acc[px] = (f4)0.f;

  for (int ky = 0; ky < 7; ++ky)
    for (int kx = 0; kx < 7; ++kx)
#pragma unroll
      for (int ci = 0; ci < 3; ++ci) {
        f4 wv = *(const f4*)&w_lds[(((ky * 7 + kx) * 3) + ci) * 64 + co];
        const float* ip = &in_lds[((2 * py + ky) * 37 + kx) * 3 + ci];
#pragma unroll
        for (int px = 0; px < 16; ++px) {
          float iv = ip[px * 6];
          acc[px] += iv * wv;
        }
      }

#pragma unroll
  for (int px = 0; px < 16; ++px) {
    int oy = ty0 + py, ox = tx0 + px;
    f4 o = acc[px];
#pragma unroll
    for (int c = 0; c < 4; ++c) o[c] = fmaxf(o[c], 0.f);
    *(f4*)&out[(oy * 256 + ox) * 64 + co] = o;
  }
}

// ---------------------------------------------------------------------------
// 3x3 implicit-GEMM conv, NHWC fp32. Block tile 128 pix x 128 co, 256 thr,
// 8x8 outputs/thread (FMA:LDS byte ratio 1.0 -> balanced pipes).
// gridDim.z splits C_in into Z slices of ci_per_z; partials written to
// pout + z*npix*C_out. relu applied only when Z==1 (direct mode).
// Requires: C_in%32==0 within slice, C_out%128==0, npix%128==0, W=1<<wshift.
// ---------------------------------------------------------------------------
__global__ __launch_bounds__(256, 2) void conv128(
    const float* __restrict__ in, const float* __restrict__ w,
    float* __restrict__ pout,
    int H_in, int W_in, int C_in, int wshift, int C_out,
    int stride, int pad, int ci_per_z, int npix, int relu)
{
  __shared__ __align__(16) float As[128][36];  // [pix][ci] (+4 pad, rows 16B-aligned)
  __shared__ __align__(16) float Bs[32][128];  // [ci][co]
  const int tid = threadIdx.x;
  const int pix_base = blockIdx.x * 128;
  const int co_base = blockIdx.y * 128;
  const int ci_z0 = blockIdx.z * ci_per_z;
  const int wmask = (1 << wshift) - 1;

  const int tx = tid & 15, ty = tid >> 4;

  // staging decode (constant per thread): A = 128x32 floats = 1024 f4, 4/thread
  int a_pix[4], a_c4[4], a_oy[4], a_ox[4];
#pragma unroll
  for (int q = 0; q < 4; ++q) {
    int f = q * 256 + tid;
    a_pix[q] = f >> 3; a_c4[q] = f & 7;
    int p = pix_base + a_pix[q];
    a_oy[q] = p >> wshift; a_ox[q] = p & wmask;
  }
  // B = 32x128 floats = 1024 f4, 4/thread
  int b_row[4], b_co4[4];
#pragma unroll
  for (int q = 0; q < 4; ++q) {
    int f = q * 256 + tid;
    b_row[q] = f >> 5; b_co4[q] = f & 31;
  }

  f4 acc0[8], acc1[8];
#pragma unroll
  for (int i = 0; i < 8; ++i) { acc0[i] = (f4)0.f; acc1[i] = (f4)0.f; }

  for (int ky = 0; ky < 3; ++ky) {
    for (int kx = 0; kx < 3; ++kx) {
      const float* aptr[4];
      bool aval[4];
#pragma unroll
      for (int q = 0; q < 4; ++q) {
        int iy = a_oy[q] * stride - pad + ky;
        int ix = a_ox[q] * stride - pad + kx;
        aval[q] = ((unsigned)iy < (unsigned)H_in) && ((unsigned)ix < (unsigned)W_in);
        aptr[q] = in + (size_t)(iy * W_in + ix) * C_in + a_c4[q] * 4;
      }
      const float* bbase = w + (size_t)((ky * 3 + kx) * C_in) * C_out + co_base;

      for (int ci = ci_z0; ci < ci_z0 + ci_per_z; ci += 32) {
        __syncthreads();  // previous compute done before overwrite
#pragma unroll
        for (int q = 0; q < 4; ++q) {
          f4 av = (f4)0.f;
          if (aval[q]) av = *(const f4*)(aptr[q] + ci);
          *(f4*)&As[a_pix[q]][a_c4[q] * 4] = av;
        }
#pragma unroll
        for (int q = 0; q < 4; ++q) {
          *(f4*)&Bs[b_row[q]][b_co4[q] * 4] =
              *(const f4*)(bbase + (size_t)(ci + b_row[q]) * C_out + b_co4[q] * 4);
        }
        __syncthreads();
#pragma unroll
        for (int kk = 0; kk < 32; kk += 4) {
          f4 a[8];
#pragma unroll
          for (int i = 0; i < 8; ++i) a[i] = *(const f4*)&As[ty * 8 + i][kk];
#pragma unroll
          for (int j = 0; j < 4; ++j) {
            f4 b0 = *(const f4*)&Bs[kk + j][tx * 8];
            f4 b1 = *(const f4*)&Bs[kk + j][tx * 8 + 4];
#pragma unroll
            for (int i = 0; i < 8; ++i) {
              float av = a[i][j];
              acc0[i] += av * b0;
              acc1[i] += av * b1;
            }
          }
        }
      }
    }
  }

  float* dst = pout + (size_t)blockIdx.z * npix * C_out;
#pragma unroll
  for (int i = 0; i < 8; ++i) {
    int p = pix_base + ty * 8 + i;
    f4 o0 = acc0[i], o1 = acc1[i];
    if (relu) {
#pragma unroll
      for (int c = 0; c < 4; ++c) { o0[c] = fmaxf(o0[c], 0.f); o1[c] = fmaxf(o1[c], 0.f); }
    }
    *(f4*)&dst[(size_t)p * C_out + co_base + tx * 8] = o0;
    *(f4*)&dst[(size_t)p * C_out + co_base + tx * 8 + 4] = o1;
  }
}

// ---------------------------------------------------------------------------
// Sum Z partial slices (f4-vectorized) + optional ReLU.
// ---------------------------------------------------------------------------
__global__ __launch_bounds__(256) void reduce_relu_kernel(
    const float* __restrict__ p, float* __restrict__ out, int n4, int Z, int relu)
{
  int idx = blockIdx.x * 256 + threadIdx.x;
  if (idx >= n4) return;
  const f4* pv = (const f4*)p;
  f4 s = pv[idx];
  for (int z = 1; z < Z; ++z) s += pv[(size_t)z * n4 + idx];
  if (relu) {
#pragma unroll
    for (int c = 0; c < 4; ++c) s[c] = fmaxf(s[c], 0.f);
  }
  ((f4*)out)[idx] = s;
}

// ---------------------------------------------------------------------------
// 1x1 conv with optional fused nearest-neighbor up2 add.
// ---------------------------------------------------------------------------
__global__ __launch_bounds__(256) void conv1x1_kernel(
    const float* __restrict__ in, const float* __restrict__ w,
    const float* __restrict__ res, float* __restrict__ out,
    int C_in, int C_out, int wshift, int add_up2)
{
  const int tid = threadIdx.x;
  const int co = blockIdx.y * 64 + (tid & 63);
  const int pg = tid >> 6;
  const int p_base = blockIdx.x * 16 + pg * 4;
  const int wmask = (1 << wshift) - 1;

  float acc[4] = {0.f, 0.f, 0.f, 0.f};
  for (int ci = 0; ci < C_in; ci += 4) {
    float w0 = w[(ci + 0) * C_out + co];
    float w1 = w[(ci + 1) * C_out + co];
    float w2 = w[(ci + 2) * C_out + co];
    float w3 = w[(ci + 3) * C_out + co];
#pragma unroll
    for (int q = 0; q < 4; ++q) {
      f4 iv = *(const f4*)&in[(p_base + q) * C_in + ci];
      acc[q] += iv[0] * w0 + iv[1] * w1 + iv[2] * w2 + iv[3] * w3;
    }
  }
#pragma unroll
  for (int q = 0; q < 4; ++q) {
    int p = p_base + q;
    float v = acc[q];
    if (add_up2) {
      int oy = p >> wshift, ox = p & wmask;
      v += res[(((oy >> 1) << (wshift - 1)) + (ox >> 1)) * C_out + co];
    }
    out[p * C_out + co] = v;
  }
}

// ---------------------------------------------------------------------------
// obj head (1x1, 256->1) + sigmoid.
// ---------------------------------------------------------------------------
__global__ __launch_bounds__(256) void obj_sigmoid_kernel(
    const float* __restrict__ t, const float* __restrict__ wobj,
    float* __restrict__ scores)
{
  __shared__ float wl[256];
  const int tid = threadIdx.x;
  wl[tid] = wobj[tid];
  __syncthreads();
  const int p = blockIdx.x * 256 + tid;
  float acc = 0.f;
  for (int ci = 0; ci < 256; ci += 4) {
    f4 tv = *(const f4*)&t[p * 256 + ci];
    acc += tv[0] * wl[ci] + tv[1] * wl[ci + 1] + tv[2] * wl[ci + 2] + tv[3] * wl[ci + 3];
  }
  scores[p] = 1.f / (1.f + expf(-acc));
}

// ---------------------------------------------------------------------------
// Greedy NMS, 100 iterations, faithful to reference.
// ---------------------------------------------------------------------------
__global__ __launch_bounds__(256) void nms_kernel(
    const float* __restrict__ scores, float* __restrict__ out)
{
  __shared__ float sw[4096];
  __shared__ float rv[4];
  __shared__ int ri[4];
  __shared__ float sel[4];
  __shared__ int selij[2];
  const int tid = threadIdx.x;
  const float inv63 = 1.0f / 63.0f;

#pragma unroll
  for (int r = 0; r < 16; ++r) sw[r * 256 + tid] = scores[r * 256 + tid];
  __syncthreads();

  for (int it = 0; it < 100; ++it) {
    float bv = -3.0e38f;
    int bi = 0;
#pragma unroll
    for (int r = 0; r < 16; ++r) {
      int k = r * 256 + tid;
      float v = sw[k];
      if (v > bv) { bv = v; bi = k; }
    }
#pragma unroll
    for (int off = 32; off > 0; off >>= 1) {
      float ov = __shfl_down(bv, off);
      int oi = __shfl_down(bi, off);
      if (ov > bv || (ov == bv && oi < bi)) { bv = ov; bi = oi; }
    }
    if ((tid & 63) == 0) { rv[tid >> 6] = bv; ri[tid >> 6] = bi; }
    __syncthreads();
    if (tid == 0) {
      float v = rv[0];
      int s = ri[0];
#pragma unroll
      for (int wv = 1; wv < 4; ++wv)
        if (rv[wv] > v || (rv[wv] == v && ri[wv] < s)) { v = rv[wv]; s = ri[wv]; }
      int si = s >> 6, sj = s & 63;
      float y = sj * inv63, x = si * inv63;
      float b0 = fmaxf(y - 0.05f, 0.f);
      float b1 = fmaxf(x - 0.05f, 0.f);
      float b2 = fminf(y + 0.05f, 1.f);
      float b3 = fminf(x + 0.05f, 1.f);
      bool valid = v > -5.0e29f;
      out[it * 4 + 0] = valid ? b0 : 0.f;
      out[it * 4 + 1] = valid ? b1 : 0.f;
      out[it * 4 + 2] = valid ? b2 : 0.f;
      out[it * 4 + 3] = valid ? b3 : 0.f;
      out[400 + it] = valid ? v : 0.f;
      sel[0] = b0; sel[1] = b1; sel[2] = b2; sel[3] = b3;
      selij[0] = si; selij[1] = sj;
    }
    __syncthreads();
    const float a0 = sel[0], a1 = sel[1], a2 = sel[2], a3 = sel[3];
    const int si = selij[0], sj = selij[1];
    const float barea = (a2 - a0) * (a3 - a1);
#pragma unroll
    for (int r = 0; r < 16; ++r) {
      int k = r * 256 + tid;
      int i = k >> 6, j = k & 63;
      int di = i - si; di = di < 0 ? -di : di;
      int dj = j - sj; dj = dj < 0 ? -dj : dj;
      if (di <= 6 && dj <= 6) {
        float y = j * inv63, x = i * inv63;
        float c0 = fmaxf(y - 0.05f, 0.f), c1 = fmaxf(x - 0.05f, 0.f);
        float c2 = fminf(y + 0.05f, 1.f), c3 = fminf(x + 0.05f, 1.f);
        float yy1 = fmaxf(a0, c0), xx1 = fmaxf(a1, c1);
        float yy2 = fminf(a2, c2), xx2 = fminf(a3, c3);
        float inter = fmaxf(yy2 - yy1, 0.f) * fmaxf(xx2 - xx1, 0.f);
        float carea = (c2 - c0) * (c3 - c1);
        float iou = inter / (barea + carea - inter + 1e-9f);
        if (iou > 0.5f) sw[k] = -1.0e30f;
      }
    }
    __syncthreads();
  }
}

// ---------------------------------------------------------------------------
extern "C" void kernel_launch(void* const* d_in, const int* in_sizes, int n_in,
                              void* d_out, int out_size, void* d_ws, size_t ws_size,
                              hipStream_t stream) {
  const float* x      = (const float*)d_in[0];
  const float* w_stem = (const float*)d_in[1];
  const float* w_c2   = (const float*)d_in[2];
  const float* w_c3   = (const float*)d_in[3];
  const float* w_c4   = (const float*)d_in[4];
  const float* w_c5   = (const float*)d_in[5];
  const float* l3     = (const float*)d_in[6];
  const float* l4     = (const float*)d_in[7];
  const float* l5     = (const float*)d_in[8];
  const float* o3w    = (const float*)d_in[9];
  const float* w_rpn  = (const float*)d_in[12];
  const float* w_obj  = (const float*)d_in[13];
  float* out = (float*)d_out;
  float* ws = (float*)d_ws;

  float* S   = ws;              // 256*256*64   = 4194304 floats
  float* C2  = S   + 4194304;   // 128*128*256  = 4194304
  float* C3  = C2  + 4194304;   // 64*64*512    = 2097152
  float* C4  = C3  + 2097152;   // 32*32*1024   = 1048576
  float* C5  = C4  + 1048576;   // 16*16*2048   = 524288
  float* P5  = C5  + 524288;    // 16*16*256    = 65536
  float* P4  = P5  + 65536;     // 32*32*256    = 262144
  float* P3P = P4  + 262144;    // 64*64*256    = 1048576
  float* P3  = P3P + 1048576;   // 1048576
  float* T   = P3  + 1048576;   // 1048576
  float* SC  = T   + 1048576;   // 4096
  // Partial-sum scratch recycles dead regions:
  //  PART_A  = S        (4.19M floats; S dead after c2 consumed it? no — S dead after c2 kernel ran)
  //  PART_AB = S..C2    (8.39M floats; valid once C2 is dead, i.e. after c3)

  // backbone
  stem_kernel<<<256, 256, 0, stream>>>(x, w_stem, S);
  // c2: 256x256x64 -> 128x128x256, Z=1 direct+relu. grid (128,2,1)
  conv128<<<dim3(128, 2, 1), 256, 0, stream>>>(
      S, w_c2, C2, 256, 256, 64, 7, 256, 2, 0, 64, 16384, 1);
  // c3: 128x128x256 -> 64x64x512, Z=2 (partial in S), reduce+relu -> C3
  conv128<<<dim3(32, 4, 2), 256, 0, stream>>>(
      C2, w_c3, S, 128, 128, 256, 6, 512, 2, 0, 128, 4096, 0);
  reduce_relu_kernel<<<2048, 256, 0, stream>>>(S, C3, 524288, 2, 1);
  // c4: 64x64x512 -> 32x32x1024, Z=8 (partial in S..C2), reduce+relu -> C4
  conv128<<<dim3(8, 8, 8), 256, 0, stream>>>(
      C3, w_c4, S, 64, 64, 512, 5, 1024, 2, 0, 64, 1024, 0);
  reduce_relu_kernel<<<1024, 256, 0, stream>>>(S, C4, 262144, 8, 1);
  // c5: 32x32x1024 -> 16x16x2048, Z=16 (partial in S..C2), reduce+relu -> C5
  conv128<<<dim3(2, 16, 16), 256, 0, stream>>>(
      C4, w_c5, S, 32, 32, 1024, 4, 2048, 2, 0, 64, 256, 0);
  reduce_relu_kernel<<<512, 256, 0, stream>>>(S, C5, 131072, 16, 1);
  // FPN laterals (+ fused up2 add)
  conv1x1_kernel<<<dim3(16, 4), 256, 0, stream>>>(C5, l5, nullptr, P5, 2048, 256, 4, 0);
  conv1x1_kernel<<<dim3(64, 4), 256, 0, stream>>>(C4, l4, P5, P4, 1024, 256, 5, 1);
  conv1x1_kernel<<<dim3(256, 4), 256, 0, stream>>>(C3, l3, P4, P3P, 512, 256, 6, 1);
  // o3: 64x64x256 -> 64x64x256, stride1 pad1, Z=8, reduce (no relu) -> P3
  conv128<<<dim3(32, 2, 8), 256, 0, stream>>>(
      P3P, o3w, S, 64, 64, 256, 6, 256, 1, 1, 32, 4096, 0);
  reduce_relu_kernel<<<1024, 256, 0, stream>>>(S, P3, 262144, 8, 0);
  // rpn: same shape, Z=8, reduce+relu -> T
  conv128<<<dim3(32, 2, 8), 256, 0, stream>>>(
      P3, w_rpn, S, 64, 64, 256, 6, 256, 1, 1, 32, 4096, 0);
  reduce_relu_kernel<<<1024, 256, 0, stream>>>(S, T, 262144, 8, 1);
  // obj head + sigmoid, then NMS
  obj_sigmoid_kernel<<<16, 256, 0, stream>>>(T, w_obj, SC);
  nms_kernel<<<1, 256, 0, stream>>>(SC, out);
}